// Round 14
// baseline (498.979 us; speedup 1.0000x reference)
//
#include <hip/hip_runtime.h>

typedef short short8 __attribute__((ext_vector_type(8)));
typedef float f32x4 __attribute__((ext_vector_type(4)));

#define HDIM 128
#define SCAN_NB 256
#define SCAN_TPB 256
// s_getreg imm: HW_REG_XCC_ID(=20) | offset 0<<6 | (32-1)<<11
#define XCC_GETREG_IMM (20 | (31 << 11))

__device__ __forceinline__ ushort f2bf(float f) {
  uint u = __float_as_uint(f);
  u += 0x7fffu + ((u >> 16) & 1u);   // round-to-nearest-even
  return (ushort)(u >> 16);
}
__device__ __forceinline__ float bflo(uint v){ return __uint_as_float(v << 16); }
__device__ __forceinline__ float bfhi(uint v){ return __uint_as_float(v & 0xffff0000u); }

// ---------------- degree count, per-XCD partitions; local-L2 atomics ----------------
__global__ __launch_bounds__(256) void k_deg(const int* __restrict__ dst, int E, int N,
                                             int* __restrict__ degc8, ushort* __restrict__ rank) {
  uint xcd = __builtin_amdgcn_s_getreg(XCC_GETREG_IMM) & 7u;
  int* plane = degc8 + (size_t)xcd * N;
  for (int e = blockIdx.x*blockDim.x + threadIdx.x; e < E; e += gridDim.x*blockDim.x) {
    int d = dst[e];
    int r = __hip_atomic_fetch_add(&plane[d], 1, __ATOMIC_RELAXED, __HIP_MEMORY_SCOPE_WORKGROUP);
    rank[e] = (ushort)((xcd << 13) | (uint)r);
  }
}

// ---------------- scan phase A: sum 8 planes -> degc total, dinv, blocksum ----------------
__global__ __launch_bounds__(SCAN_TPB) void k_scanA(const int* __restrict__ degc8, int N,
    int* __restrict__ degc, int* __restrict__ blocksum, float* __restrict__ dinv) {
  int ipt = (N + SCAN_NB*SCAN_TPB - 1) / (SCAN_NB*SCAN_TPB);
  int chunk = ipt * SCAN_TPB;
  int start = blockIdx.x * chunk + threadIdx.x * ipt;
  int s = 0;
  #pragma unroll
  for (int k = 0; k < 4; ++k) {
    if (k < ipt) {
      int i = start + k;
      if (i < N) {
        int d = 0;
        #pragma unroll
        for (int x = 0; x < 8; ++x) d += degc8[(size_t)x*N + i];
        degc[i] = d;
        s += d;
        dinv[i] = rsqrtf((float)d + 1.0f);
      }
    }
  }
  __shared__ int red[SCAN_TPB];
  int t = threadIdx.x;
  red[t] = s; __syncthreads();
  for (int off = SCAN_TPB/2; off > 0; off >>= 1) {
    if (t < off) red[t] += red[t+off];
    __syncthreads();
  }
  if (t == 0) blocksum[blockIdx.x] = red[0];
}

// ---------------- scan phase B (block 0) + graph bounds (block 1) ----------------
__global__ __launch_bounds__(SCAN_NB) void k_scanB(const int* __restrict__ blocksum,
    int* __restrict__ blockoff, int* __restrict__ totalN,
    const int* __restrict__ batch, int N, int G, float* __restrict__ inv_cnt) {
  int t = threadIdx.x;
  if (blockIdx.x == 0) {
    __shared__ int sh[SCAN_NB];
    sh[t] = blocksum[t];
    __syncthreads();
    for (int off = 1; off < SCAN_NB; off <<= 1) {
      int v = (t >= off) ? sh[t-off] : 0;
      __syncthreads();
      sh[t] += v;
      __syncthreads();
    }
    blockoff[t] = (t == 0) ? 0 : sh[t-1];
    if (t == SCAN_NB-1) *totalN = sh[t];
  } else {
    __shared__ int bnd[SCAN_NB+1];
    if (t <= G) {
      int lo = 0, hi = N;
      while (lo < hi) { int mid = (lo + hi) >> 1; if (batch[mid] < t) lo = mid + 1; else hi = mid; }
      bnd[t] = lo;
    }
    __syncthreads();
    if (t < G) {
      int c = bnd[t+1] - bnd[t];
      inv_cnt[t] = 1.0f / (float)max(c, 1);
    }
  }
}

// ---------------- scan phase C: row_ptr + per-XCD sub-offsets row_ptr8 ----------------
__global__ __launch_bounds__(SCAN_TPB) void k_scanC(const int* __restrict__ degc,
    const int* __restrict__ degc8, int N,
    const int* __restrict__ blockoff, const int* __restrict__ totalN,
    int* __restrict__ row_ptr, int* __restrict__ row_ptr8) {
  int ipt = (N + SCAN_NB*SCAN_TPB - 1) / (SCAN_NB*SCAN_TPB);
  int chunk = ipt * SCAN_TPB;
  int start = blockIdx.x * chunk + threadIdx.x * ipt;
  int t = threadIdx.x;
  int vals[4];
  int s = 0;
  #pragma unroll
  for (int k = 0; k < 4; ++k) {
    int v = 0;
    if (k < ipt) { int i = start + k; if (i < N) v = degc[i]; }
    vals[k] = v; s += v;
  }
  __shared__ int sh[SCAN_TPB];
  sh[t] = s; __syncthreads();
  for (int off = 1; off < SCAN_TPB; off <<= 1) {
    int v = (t >= off) ? sh[t-off] : 0;
    __syncthreads();
    sh[t] += v;
    __syncthreads();
  }
  int run = blockoff[blockIdx.x] + ((t == 0) ? 0 : sh[t-1]);
  #pragma unroll
  for (int k = 0; k < 4; ++k) {
    if (k < ipt) {
      int i = start + k;
      if (i < N) {
        row_ptr[i] = run;
        int c = run;
        #pragma unroll
        for (int x = 0; x < 8; ++x) {
          row_ptr8[(size_t)x*N + i] = c;
          c += degc8[(size_t)x*N + i];
        }
      }
    }
    run += vals[k];
  }
  if (blockIdx.x == 0 && t == 0) row_ptr[N] = *totalN;
}

// ---------------- fill CSR (atomic-free): pos = row_ptr8[xcd][dst] + r ----------------
__global__ __launch_bounds__(256) void k_fill(const int* __restrict__ src, const int* __restrict__ dst, int E, int N,
    const float* __restrict__ dinv, const int* __restrict__ row_ptr8, const ushort* __restrict__ rank,
    int2* __restrict__ epack) {
  for (int e = blockIdx.x*blockDim.x + threadIdx.x; e < E; e += gridDim.x*blockDim.x) {
    int s = src[e], d = dst[e];
    uint rk = rank[e];
    uint xcd = rk >> 13;
    int  r   = (int)(rk & 0x1FFFu);
    int pos = row_ptr8[(size_t)xcd*N + d] + r;
    float cf = dinv[s] * dinv[d];
    epack[pos] = make_int2(s, __float_as_int(cf));
  }
}

// ---------------- GEMM: xw(bf16) = in @ W (R10-proven grid-stride form) ----------------
template<int IN_F32>
__global__ __launch_bounds__(256,1) void k_gemm(const void* __restrict__ in_, const float* __restrict__ W,
    ushort* __restrict__ xw, int N) {
  int lane = threadIdx.x & 63;
  int wid  = (blockIdx.x * blockDim.x + threadIdx.x) >> 6;
  int nw   = (gridDim.x * blockDim.x) >> 6;
  int colB = lane & 15;
  int krow = (lane >> 4) * 8;

  short8 bfr[8][4];
  #pragma unroll
  for (int nt = 0; nt < 8; ++nt)
    #pragma unroll
    for (int kc = 0; kc < 4; ++kc) {
      short8 t;
      #pragma unroll
      for (int j = 0; j < 8; ++j)
        t[j] = (short)f2bf(W[(kc*32 + krow + j)*HDIM + nt*16 + colB]);
      bfr[nt][kc] = t;
    }

  int strips = (N + 15) >> 4;
  for (int s = wid; s < strips; s += nw) {
    int ra = s*16 + (lane & 15);
    bool va = ra < N;
    short8 a[4];
    if (IN_F32) {
      const float* xin = (const float*)in_;
      #pragma unroll
      for (int kc = 0; kc < 4; ++kc) {
        short8 t = {0,0,0,0,0,0,0,0};
        if (va) {
          const float* p = xin + (size_t)ra*HDIM + kc*32 + krow;
          float4 lo4 = *(const float4*)p;
          float4 hi4 = *(const float4*)(p+4);
          t[0]=(short)f2bf(lo4.x); t[1]=(short)f2bf(lo4.y); t[2]=(short)f2bf(lo4.z); t[3]=(short)f2bf(lo4.w);
          t[4]=(short)f2bf(hi4.x); t[5]=(short)f2bf(hi4.y); t[6]=(short)f2bf(hi4.z); t[7]=(short)f2bf(hi4.w);
        }
        a[kc] = t;
      }
    } else {
      const ushort* hin = (const ushort*)in_;
      #pragma unroll
      for (int kc = 0; kc < 4; ++kc) {
        short8 t = {0,0,0,0,0,0,0,0};
        if (va) t = *(const short8*)(hin + (size_t)ra*HDIM + kc*32 + krow);
        a[kc] = t;
      }
    }
    f32x4 acc[8];
    #pragma unroll
    for (int nt = 0; nt < 8; ++nt) { acc[nt][0]=0.f; acc[nt][1]=0.f; acc[nt][2]=0.f; acc[nt][3]=0.f; }
    #pragma unroll
    for (int nt = 0; nt < 8; ++nt)
      #pragma unroll
      for (int kc = 0; kc < 4; ++kc)
        acc[nt] = __builtin_amdgcn_mfma_f32_16x16x32_bf16(a[kc], bfr[nt][kc], acc[nt], 0, 0, 0);

    int r0 = s*16 + (lane>>4)*4;
    #pragma unroll
    for (int nt = 0; nt < 8; ++nt) {
      int c = nt*16 + (lane&15);
      #pragma unroll
      for (int rg = 0; rg < 4; ++rg) {
        int rr = r0 + rg;
        if (rr < N) xw[(size_t)rr*HDIM + c] = f2bf(acc[nt][rg]);
      }
    }
  }
}

// ---------------- aggregation v3: scalar-pipe edge records + 16-deep uniform-row gathers ----------------
// Edge stream per node is wave-uniform & contiguous -> uniform index loads compile to
// s_load batches (SGPR), freeing the DS/VALU pipes (no shfl) and overlapping edge-record
// fetch (lgkmcnt) with row-gather drain (vmcnt). Tail uses uniform select to e0 with
// cf=0 (same-row dummy gathers, L2-hit).
__global__ __launch_bounds__(256) void k_agg(const uint* __restrict__ xwu, const int2* __restrict__ epack,
    const int* __restrict__ row_ptr, const float* __restrict__ dinv, const float* __restrict__ bias,
    uint* __restrict__ hu, int N) {
  int lane = threadIdx.x & 63;
  int n = blockIdx.x*4 + (threadIdx.x >> 6);
  if (n >= N) return;
  int e0 = row_ptr[n], e1 = row_ptr[n+1];
  float a0 = 0.f, a1 = 0.f;
  for (int e = e0; e < e1; e += 16) {
    int sN[16]; float cf[16];
    #pragma unroll
    for (int u = 0; u < 16; ++u) {
      int ee = e + u;
      int idx = (ee < e1) ? ee : e0;       // uniform select: scalar loads stay scalar
      int2 p = epack[idx];
      sN[u] = p.x;
      cf[u] = (ee < e1) ? __int_as_float(p.y) : 0.0f;
    }
    #pragma unroll
    for (int u = 0; u < 16; ++u) {
      uint v = xwu[(size_t)sN[u]*64 + lane];
      a0 += cf[u] * bflo(v);
      a1 += cf[u] * bfhi(v);
    }
  }
  float di = dinv[n]; float w = di*di;
  uint v = xwu[(size_t)n*64 + lane];
  a0 += w * bflo(v);
  a1 += w * bfhi(v);
  a0 += bias[lane*2];  a1 += bias[lane*2+1];
  a0 = fmaxf(a0, 0.f); a1 = fmaxf(a1, 0.f);
  uint o = ((uint)f2bf(a0)) | (((uint)f2bf(a1)) << 16);
  hu[(size_t)n*64 + lane] = o;
}

// ---------------- pooling: segmented accumulate (batch sorted) ----------------
__global__ __launch_bounds__(256) void k_pool(const uint* __restrict__ hu, const int* __restrict__ batch,
    float* __restrict__ psum, int N) {
  int lane = threadIdx.x & 63;
  int wave = threadIdx.x >> 6;
  int n0 = blockIdx.x*512 + wave*128;
  if (n0 >= N) return;
  int n1 = min(n0 + 128, N);
  float a0 = 0.f, a1 = 0.f;
  int gc = batch[n0];
  for (int n = n0; n < n1; ++n) {
    int g = batch[n];
    if (g != gc) {
      atomicAdd(&psum[gc*HDIM + lane*2],   a0);
      atomicAdd(&psum[gc*HDIM + lane*2+1], a1);
      a0 = 0.f; a1 = 0.f; gc = g;
    }
    uint v = hu[(size_t)n*64 + lane];
    a0 += bflo(v); a1 += bfhi(v);
  }
  atomicAdd(&psum[gc*HDIM + lane*2],   a0);
  atomicAdd(&psum[gc*HDIM + lane*2+1], a1);
}

// ---------------- final linear ----------------
__global__ __launch_bounds__(256) void k_final(const float* __restrict__ psum, const float* __restrict__ inv_cnt,
    const float* __restrict__ Wlin, const float* __restrict__ blin, float* __restrict__ out, int G, int C) {
  int idx = blockIdx.x*256 + threadIdx.x;
  if (idx >= G*C) return;
  int g = idx / C, c = idx % C;
  float acc = 0.f;
  for (int k = 0; k < HDIM; ++k) acc += psum[g*HDIM + k] * Wlin[k*C + c];
  out[idx] = acc * inv_cnt[g] + blin[c];
}

extern "C" void kernel_launch(void* const* d_in, const int* in_sizes, int n_in,
                              void* d_out, int out_size, void* d_ws, size_t ws_size,
                              hipStream_t stream) {
  const float* x    = (const float*)d_in[0];
  const int*   ei   = (const int*)d_in[1];
  const int*   batch= (const int*)d_in[2];
  const float* W0   = (const float*)d_in[3];
  const float* b0   = (const float*)d_in[4];
  const float* W1   = (const float*)d_in[5];
  const float* b1   = (const float*)d_in[6];
  const float* W2   = (const float*)d_in[7];
  const float* b2   = (const float*)d_in[8];
  const float* Wlin = (const float*)d_in[9];
  const float* blin = (const float*)d_in[10];

  int N = in_sizes[0] / HDIM;
  int E = in_sizes[1] / 2;
  int C = in_sizes[10];
  int G = out_size / C;
  const int* src = ei;
  const int* dst = ei + E;

  char* ws = (char*)d_ws;
  size_t o = 0;
  auto alloc = [&](size_t bytes){ size_t r = o; o += (bytes + 511) & ~(size_t)511; return r; };
  size_t zbeg  = o;
  int*    degc8   = (int*)   (ws + alloc((size_t)8*N*4));
  float*  psum    = (float*) (ws + alloc((size_t)G*HDIM*4));
  size_t zend  = o;
  int*    degc    = (int*)   (ws + alloc((size_t)N*4));
  float*  dinv    = (float*) (ws + alloc((size_t)N*4));
  int*    row_ptr = (int*)   (ws + alloc((size_t)(N+1)*4));
  int*    row_ptr8= (int*)   (ws + alloc((size_t)8*N*4));
  float*  inv_cnt = (float*) (ws + alloc((size_t)G*4));
  int*    blocksum= (int*)   (ws + alloc((size_t)SCAN_NB*4));
  int*    blockoff= (int*)   (ws + alloc((size_t)SCAN_NB*4));
  int*    totalN  = (int*)   (ws + alloc(4));
  ushort* rank    = (ushort*)(ws + alloc((size_t)E*2));
  int2*   epack   = (int2*)  (ws + alloc((size_t)E*8));
  ushort* xw      = (ushort*)(ws + alloc((size_t)N*HDIM*2));
  ushort* hbuf    = (ushort*)(ws + alloc((size_t)N*HDIM*2));

  hipMemsetAsync(ws + zbeg, 0, zend - zbeg, stream);

  k_deg  <<<2048, 256, 0, stream>>>(dst, E, N, degc8, rank);
  k_scanA<<<SCAN_NB, SCAN_TPB, 0, stream>>>(degc8, N, degc, blocksum, dinv);
  k_scanB<<<2, SCAN_NB, 0, stream>>>(blocksum, blockoff, totalN, batch, N, G, inv_cnt);
  k_scanC<<<SCAN_NB, SCAN_TPB, 0, stream>>>(degc, degc8, N, blockoff, totalN, row_ptr, row_ptr8);
  k_fill <<<2048, 256, 0, stream>>>(src, dst, E, N, dinv, row_ptr8, rank, epack);

  const int gemm_blocks = 512;
  const int agg_blocks  = (N + 3) / 4;

  // layer 0
  k_gemm<1><<<gemm_blocks, 256, 0, stream>>>((const void*)x, W0, xw, N);
  k_agg<<<agg_blocks, 256, 0, stream>>>((const uint*)xw, epack, row_ptr, dinv, b0, (uint*)hbuf, N);
  // layer 1
  k_gemm<0><<<gemm_blocks, 256, 0, stream>>>((const void*)hbuf, W1, xw, N);
  k_agg<<<agg_blocks, 256, 0, stream>>>((const uint*)xw, epack, row_ptr, dinv, b1, (uint*)hbuf, N);
  // layer 2
  k_gemm<0><<<gemm_blocks, 256, 0, stream>>>((const void*)hbuf, W2, xw, N);
  k_agg<<<agg_blocks, 256, 0, stream>>>((const uint*)xw, epack, row_ptr, dinv, b2, (uint*)hbuf, N);

  k_pool<<<(N + 511)/512, 256, 0, stream>>>((const uint*)hbuf, batch, psum, N);
  k_final<<<(G*C + 255)/256, 256, 0, stream>>>(psum, inv_cnt, Wlin, blin, (float*)d_out, G, C);
}

// Round 15
// 417.761 us; speedup vs baseline: 1.1944x; 1.1944x over previous
//
#include <hip/hip_runtime.h>

typedef short short8 __attribute__((ext_vector_type(8)));
typedef float f32x4 __attribute__((ext_vector_type(4)));

#define HDIM 128
#define SCAN_NB 256
#define SCAN_TPB 256
// s_getreg imm: HW_REG_XCC_ID(=20) | offset 0<<6 | (32-1)<<11
#define XCC_GETREG_IMM (20 | (31 << 11))

__device__ __forceinline__ ushort f2bf(float f) {
  uint u = __float_as_uint(f);
  u += 0x7fffu + ((u >> 16) & 1u);   // round-to-nearest-even
  return (ushort)(u >> 16);
}
__device__ __forceinline__ float bflo(uint v){ return __uint_as_float(v << 16); }
__device__ __forceinline__ float bfhi(uint v){ return __uint_as_float(v & 0xffff0000u); }

// ---------------- degree count, per-XCD partitions; local-L2 atomics ----------------
__global__ __launch_bounds__(256) void k_deg(const int* __restrict__ dst, int E, int N,
                                             int* __restrict__ degc8, ushort* __restrict__ rank) {
  uint xcd = __builtin_amdgcn_s_getreg(XCC_GETREG_IMM) & 7u;
  int* plane = degc8 + (size_t)xcd * N;
  for (int e = blockIdx.x*blockDim.x + threadIdx.x; e < E; e += gridDim.x*blockDim.x) {
    int d = dst[e];
    int r = __hip_atomic_fetch_add(&plane[d], 1, __ATOMIC_RELAXED, __HIP_MEMORY_SCOPE_WORKGROUP);
    rank[e] = (ushort)((xcd << 13) | (uint)r);
  }
}

// ---------------- scan phase A: sum 8 planes -> degc total, dinv, blocksum ----------------
__global__ __launch_bounds__(SCAN_TPB) void k_scanA(const int* __restrict__ degc8, int N,
    int* __restrict__ degc, int* __restrict__ blocksum, float* __restrict__ dinv) {
  int ipt = (N + SCAN_NB*SCAN_TPB - 1) / (SCAN_NB*SCAN_TPB);
  int chunk = ipt * SCAN_TPB;
  int start = blockIdx.x * chunk + threadIdx.x * ipt;
  int s = 0;
  #pragma unroll
  for (int k = 0; k < 4; ++k) {
    if (k < ipt) {
      int i = start + k;
      if (i < N) {
        int d = 0;
        #pragma unroll
        for (int x = 0; x < 8; ++x) d += degc8[(size_t)x*N + i];
        degc[i] = d;
        s += d;
        dinv[i] = rsqrtf((float)d + 1.0f);
      }
    }
  }
  __shared__ int red[SCAN_TPB];
  int t = threadIdx.x;
  red[t] = s; __syncthreads();
  for (int off = SCAN_TPB/2; off > 0; off >>= 1) {
    if (t < off) red[t] += red[t+off];
    __syncthreads();
  }
  if (t == 0) blocksum[blockIdx.x] = red[0];
}

// ---------------- scan phase B (block 0) + graph bounds (block 1) ----------------
__global__ __launch_bounds__(SCAN_NB) void k_scanB(const int* __restrict__ blocksum,
    int* __restrict__ blockoff, int* __restrict__ totalN,
    const int* __restrict__ batch, int N, int G, float* __restrict__ inv_cnt) {
  int t = threadIdx.x;
  if (blockIdx.x == 0) {
    __shared__ int sh[SCAN_NB];
    sh[t] = blocksum[t];
    __syncthreads();
    for (int off = 1; off < SCAN_NB; off <<= 1) {
      int v = (t >= off) ? sh[t-off] : 0;
      __syncthreads();
      sh[t] += v;
      __syncthreads();
    }
    blockoff[t] = (t == 0) ? 0 : sh[t-1];
    if (t == SCAN_NB-1) *totalN = sh[t];
  } else {
    __shared__ int bnd[SCAN_NB+1];
    if (t <= G) {
      int lo = 0, hi = N;
      while (lo < hi) { int mid = (lo + hi) >> 1; if (batch[mid] < t) lo = mid + 1; else hi = mid; }
      bnd[t] = lo;
    }
    __syncthreads();
    if (t < G) {
      int c = bnd[t+1] - bnd[t];
      inv_cnt[t] = 1.0f / (float)max(c, 1);
    }
  }
}

// ---------------- scan phase C: row_ptr + per-XCD sub-offsets row_ptr8 ----------------
__global__ __launch_bounds__(SCAN_TPB) void k_scanC(const int* __restrict__ degc,
    const int* __restrict__ degc8, int N,
    const int* __restrict__ blockoff, const int* __restrict__ totalN,
    int* __restrict__ row_ptr, int* __restrict__ row_ptr8) {
  int ipt = (N + SCAN_NB*SCAN_TPB - 1) / (SCAN_NB*SCAN_TPB);
  int chunk = ipt * SCAN_TPB;
  int start = blockIdx.x * chunk + threadIdx.x * ipt;
  int t = threadIdx.x;
  int vals[4];
  int s = 0;
  #pragma unroll
  for (int k = 0; k < 4; ++k) {
    int v = 0;
    if (k < ipt) { int i = start + k; if (i < N) v = degc[i]; }
    vals[k] = v; s += v;
  }
  __shared__ int sh[SCAN_TPB];
  sh[t] = s; __syncthreads();
  for (int off = 1; off < SCAN_TPB; off <<= 1) {
    int v = (t >= off) ? sh[t-off] : 0;
    __syncthreads();
    sh[t] += v;
    __syncthreads();
  }
  int run = blockoff[blockIdx.x] + ((t == 0) ? 0 : sh[t-1]);
  #pragma unroll
  for (int k = 0; k < 4; ++k) {
    if (k < ipt) {
      int i = start + k;
      if (i < N) {
        row_ptr[i] = run;
        int c = run;
        #pragma unroll
        for (int x = 0; x < 8; ++x) {
          row_ptr8[(size_t)x*N + i] = c;
          c += degc8[(size_t)x*N + i];
        }
      }
    }
    run += vals[k];
  }
  if (blockIdx.x == 0 && t == 0) row_ptr[N] = *totalN;
}

// ---------------- fill CSR (atomic-free): pos = row_ptr8[xcd][dst] + r ----------------
__global__ __launch_bounds__(256) void k_fill(const int* __restrict__ src, const int* __restrict__ dst, int E, int N,
    const float* __restrict__ dinv, const int* __restrict__ row_ptr8, const ushort* __restrict__ rank,
    int2* __restrict__ epack) {
  for (int e = blockIdx.x*blockDim.x + threadIdx.x; e < E; e += gridDim.x*blockDim.x) {
    int s = src[e], d = dst[e];
    uint rk = rank[e];
    uint xcd = rk >> 13;
    int  r   = (int)(rk & 0x1FFFu);
    int pos = row_ptr8[(size_t)xcd*N + d] + r;
    float cf = dinv[s] * dinv[d];
    epack[pos] = make_int2(s, __float_as_int(cf));
  }
}

// ---------------- GEMM: xw(bf16) = in @ W (R10-proven grid-stride form) ----------------
template<int IN_F32>
__global__ __launch_bounds__(256,1) void k_gemm(const void* __restrict__ in_, const float* __restrict__ W,
    ushort* __restrict__ xw, int N) {
  int lane = threadIdx.x & 63;
  int wid  = (blockIdx.x * blockDim.x + threadIdx.x) >> 6;
  int nw   = (gridDim.x * blockDim.x) >> 6;
  int colB = lane & 15;
  int krow = (lane >> 4) * 8;

  short8 bfr[8][4];
  #pragma unroll
  for (int nt = 0; nt < 8; ++nt)
    #pragma unroll
    for (int kc = 0; kc < 4; ++kc) {
      short8 t;
      #pragma unroll
      for (int j = 0; j < 8; ++j)
        t[j] = (short)f2bf(W[(kc*32 + krow + j)*HDIM + nt*16 + colB]);
      bfr[nt][kc] = t;
    }

  int strips = (N + 15) >> 4;
  for (int s = wid; s < strips; s += nw) {
    int ra = s*16 + (lane & 15);
    bool va = ra < N;
    short8 a[4];
    if (IN_F32) {
      const float* xin = (const float*)in_;
      #pragma unroll
      for (int kc = 0; kc < 4; ++kc) {
        short8 t = {0,0,0,0,0,0,0,0};
        if (va) {
          const float* p = xin + (size_t)ra*HDIM + kc*32 + krow;
          float4 lo4 = *(const float4*)p;
          float4 hi4 = *(const float4*)(p+4);
          t[0]=(short)f2bf(lo4.x); t[1]=(short)f2bf(lo4.y); t[2]=(short)f2bf(lo4.z); t[3]=(short)f2bf(lo4.w);
          t[4]=(short)f2bf(hi4.x); t[5]=(short)f2bf(hi4.y); t[6]=(short)f2bf(hi4.z); t[7]=(short)f2bf(hi4.w);
        }
        a[kc] = t;
      }
    } else {
      const ushort* hin = (const ushort*)in_;
      #pragma unroll
      for (int kc = 0; kc < 4; ++kc) {
        short8 t = {0,0,0,0,0,0,0,0};
        if (va) t = *(const short8*)(hin + (size_t)ra*HDIM + kc*32 + krow);
        a[kc] = t;
      }
    }
    f32x4 acc[8];
    #pragma unroll
    for (int nt = 0; nt < 8; ++nt) { acc[nt][0]=0.f; acc[nt][1]=0.f; acc[nt][2]=0.f; acc[nt][3]=0.f; }
    #pragma unroll
    for (int nt = 0; nt < 8; ++nt)
      #pragma unroll
      for (int kc = 0; kc < 4; ++kc)
        acc[nt] = __builtin_amdgcn_mfma_f32_16x16x32_bf16(a[kc], bfr[nt][kc], acc[nt], 0, 0, 0);

    int r0 = s*16 + (lane>>4)*4;
    #pragma unroll
    for (int nt = 0; nt < 8; ++nt) {
      int c = nt*16 + (lane&15);
      #pragma unroll
      for (int rg = 0; rg < 4; ++rg) {
        int rr = r0 + rg;
        if (rr < N) xw[(size_t)rr*HDIM + c] = f2bf(acc[nt][rg]);
      }
    }
  }
}

// ---------------- aggregation (R12-proven): shfl-broadcast, 16 uniform-row gathers in flight ----------------
__global__ __launch_bounds__(256) void k_agg(const uint* __restrict__ xwu, const int2* __restrict__ epack,
    const int* __restrict__ row_ptr, const float* __restrict__ dinv, const float* __restrict__ bias,
    uint* __restrict__ hu, int N) {
  int lane = threadIdx.x & 63;
  int n = blockIdx.x*4 + (threadIdx.x >> 6);
  if (n >= N) return;
  int e0 = row_ptr[n], e1 = row_ptr[n+1];
  float a0 = 0.f, a1 = 0.f;
  for (int base = e0; base < e1; base += 64) {
    int cnt = min(64, e1 - base);
    int2 myp = make_int2(0, 0);            // lanes >= cnt: src=0, coef=0 (harmless dummy)
    if (lane < cnt) myp = epack[base + lane];
    for (int j = 0; j < cnt; j += 16) {
      #pragma unroll
      for (int u = 0; u < 16; ++u) {
        int idx = j + u;
        int   sN = __shfl(myp.x, idx);
        float cf = __int_as_float(__shfl(myp.y, idx));
        uint v = xwu[(size_t)sN*64 + lane];
        a0 += cf * bflo(v);
        a1 += cf * bfhi(v);
      }
    }
  }
  float di = dinv[n]; float w = di*di;
  uint v = xwu[(size_t)n*64 + lane];
  a0 += w * bflo(v);
  a1 += w * bfhi(v);
  a0 += bias[lane*2];  a1 += bias[lane*2+1];
  a0 = fmaxf(a0, 0.f); a1 = fmaxf(a1, 0.f);
  uint o = ((uint)f2bf(a0)) | (((uint)f2bf(a1)) << 16);
  hu[(size_t)n*64 + lane] = o;
}

// ---------------- pooling: segmented accumulate (batch sorted) ----------------
__global__ __launch_bounds__(256) void k_pool(const uint* __restrict__ hu, const int* __restrict__ batch,
    float* __restrict__ psum, int N) {
  int lane = threadIdx.x & 63;
  int wave = threadIdx.x >> 6;
  int n0 = blockIdx.x*512 + wave*128;
  if (n0 >= N) return;
  int n1 = min(n0 + 128, N);
  float a0 = 0.f, a1 = 0.f;
  int gc = batch[n0];
  for (int n = n0; n < n1; ++n) {
    int g = batch[n];
    if (g != gc) {
      atomicAdd(&psum[gc*HDIM + lane*2],   a0);
      atomicAdd(&psum[gc*HDIM + lane*2+1], a1);
      a0 = 0.f; a1 = 0.f; gc = g;
    }
    uint v = hu[(size_t)n*64 + lane];
    a0 += bflo(v); a1 += bfhi(v);
  }
  atomicAdd(&psum[gc*HDIM + lane*2],   a0);
  atomicAdd(&psum[gc*HDIM + lane*2+1], a1);
}

// ---------------- final linear ----------------
__global__ __launch_bounds__(256) void k_final(const float* __restrict__ psum, const float* __restrict__ inv_cnt,
    const float* __restrict__ Wlin, const float* __restrict__ blin, float* __restrict__ out, int G, int C) {
  int idx = blockIdx.x*256 + threadIdx.x;
  if (idx >= G*C) return;
  int g = idx / C, c = idx % C;
  float acc = 0.f;
  for (int k = 0; k < HDIM; ++k) acc += psum[g*HDIM + k] * Wlin[k*C + c];
  out[idx] = acc * inv_cnt[g] + blin[c];
}

extern "C" void kernel_launch(void* const* d_in, const int* in_sizes, int n_in,
                              void* d_out, int out_size, void* d_ws, size_t ws_size,
                              hipStream_t stream) {
  const float* x    = (const float*)d_in[0];
  const int*   ei   = (const int*)d_in[1];
  const int*   batch= (const int*)d_in[2];
  const float* W0   = (const float*)d_in[3];
  const float* b0   = (const float*)d_in[4];
  const float* W1   = (const float*)d_in[5];
  const float* b1   = (const float*)d_in[6];
  const float* W2   = (const float*)d_in[7];
  const float* b2   = (const float*)d_in[8];
  const float* Wlin = (const float*)d_in[9];
  const float* blin = (const float*)d_in[10];

  int N = in_sizes[0] / HDIM;
  int E = in_sizes[1] / 2;
  int C = in_sizes[10];
  int G = out_size / C;
  const int* src = ei;
  const int* dst = ei + E;

  char* ws = (char*)d_ws;
  size_t o = 0;
  auto alloc = [&](size_t bytes){ size_t r = o; o += (bytes + 511) & ~(size_t)511; return r; };
  size_t zbeg  = o;
  int*    degc8   = (int*)   (ws + alloc((size_t)8*N*4));
  float*  psum    = (float*) (ws + alloc((size_t)G*HDIM*4));
  size_t zend  = o;
  int*    degc    = (int*)   (ws + alloc((size_t)N*4));
  float*  dinv    = (float*) (ws + alloc((size_t)N*4));
  int*    row_ptr = (int*)   (ws + alloc((size_t)(N+1)*4));
  int*    row_ptr8= (int*)   (ws + alloc((size_t)8*N*4));
  float*  inv_cnt = (float*) (ws + alloc((size_t)G*4));
  int*    blocksum= (int*)   (ws + alloc((size_t)SCAN_NB*4));
  int*    blockoff= (int*)   (ws + alloc((size_t)SCAN_NB*4));
  int*    totalN  = (int*)   (ws + alloc(4));
  ushort* rank    = (ushort*)(ws + alloc((size_t)E*2));
  int2*   epack   = (int2*)  (ws + alloc((size_t)E*8));
  ushort* xw      = (ushort*)(ws + alloc((size_t)N*HDIM*2));
  ushort* hbuf    = (ushort*)(ws + alloc((size_t)N*HDIM*2));

  hipMemsetAsync(ws + zbeg, 0, zend - zbeg, stream);

  k_deg  <<<2048, 256, 0, stream>>>(dst, E, N, degc8, rank);
  k_scanA<<<SCAN_NB, SCAN_TPB, 0, stream>>>(degc8, N, degc, blocksum, dinv);
  k_scanB<<<2, SCAN_NB, 0, stream>>>(blocksum, blockoff, totalN, batch, N, G, inv_cnt);
  k_scanC<<<SCAN_NB, SCAN_TPB, 0, stream>>>(degc, degc8, N, blockoff, totalN, row_ptr, row_ptr8);
  k_fill <<<2048, 256, 0, stream>>>(src, dst, E, N, dinv, row_ptr8, rank, epack);

  const int gemm_blocks = 256;   // 1 block/CU, ~6 strips/wave: amortize W-preamble
  const int agg_blocks  = (N + 3) / 4;

  // layer 0
  k_gemm<1><<<gemm_blocks, 256, 0, stream>>>((const void*)x, W0, xw, N);
  k_agg<<<agg_blocks, 256, 0, stream>>>((const uint*)xw, epack, row_ptr, dinv, b0, (uint*)hbuf, N);
  // layer 1
  k_gemm<0><<<gemm_blocks, 256, 0, stream>>>((const void*)hbuf, W1, xw, N);
  k_agg<<<agg_blocks, 256, 0, stream>>>((const uint*)xw, epack, row_ptr, dinv, b1, (uint*)hbuf, N);
  // layer 2
  k_gemm<0><<<gemm_blocks, 256, 0, stream>>>((const void*)hbuf, W2, xw, N);
  k_agg<<<agg_blocks, 256, 0, stream>>>((const uint*)xw, epack, row_ptr, dinv, b2, (uint*)hbuf, N);

  k_pool<<<(N + 511)/512, 256, 0, stream>>>((const uint*)hbuf, batch, psum, N);
  k_final<<<(G*C + 255)/256, 256, 0, stream>>>(psum, inv_cnt, Wlin, blin, (float*)d_out, G, C);
}

// Round 16
// 400.911 us; speedup vs baseline: 1.2446x; 1.0420x over previous
//
#include <hip/hip_runtime.h>

typedef short short8 __attribute__((ext_vector_type(8)));
typedef float f32x4 __attribute__((ext_vector_type(4)));

#define HDIM 128
#define SCAN_NB 256
#define SCAN_TPB 256
// s_getreg imm: HW_REG_XCC_ID(=20) | offset 0<<6 | (32-1)<<11
#define XCC_GETREG_IMM (20 | (31 << 11))

__device__ __forceinline__ ushort f2bf(float f) {
  uint u = __float_as_uint(f);
  u += 0x7fffu + ((u >> 16) & 1u);   // round-to-nearest-even
  return (ushort)(u >> 16);
}
__device__ __forceinline__ float bflo(uint v){ return __uint_as_float(v << 16); }
__device__ __forceinline__ float bfhi(uint v){ return __uint_as_float(v & 0xffff0000u); }

// ---------------- W -> fragment-ordered bf16 image (once per launch, all 3 layers) ----------------
// wf[((nt*4+kc)*64+lane)*8+j] = bf16(W[(kc*32+(lane>>4)*8+j)*128 + nt*16+(lane&15)])
// gemm waves then load fragments as 32 coalesced dwordx4 instead of 256 scattered dwords.
__global__ __launch_bounds__(256) void k_wconv(const float* __restrict__ W0, const float* __restrict__ W1,
    const float* __restrict__ W2, ushort* __restrict__ wf) {
  int b = blockIdx.x;
  const float* W = (b < 8) ? W0 : (b < 16) ? W1 : W2;
  ushort* out = wf + (size_t)(b >> 3) * 16384;
  int g = (b & 7) * 256 + threadIdx.x;      // group in [0, 2048)
  int nt = g >> 8, kc = (g >> 6) & 3, lane = g & 63;
  int colB = lane & 15, krow = (lane >> 4) * 8;
  ushort v[8];
  #pragma unroll
  for (int j = 0; j < 8; ++j)
    v[j] = f2bf(W[(kc*32 + krow + j)*HDIM + nt*16 + colB]);
  #pragma unroll
  for (int j = 0; j < 8; ++j) out[(size_t)g*8 + j] = v[j];
}

// ---------------- degree count, per-XCD partitions; local-L2 atomics ----------------
__global__ __launch_bounds__(256) void k_deg(const int* __restrict__ dst, int E, int N,
                                             int* __restrict__ degc8, ushort* __restrict__ rank) {
  uint xcd = __builtin_amdgcn_s_getreg(XCC_GETREG_IMM) & 7u;
  int* plane = degc8 + (size_t)xcd * N;
  for (int e = blockIdx.x*blockDim.x + threadIdx.x; e < E; e += gridDim.x*blockDim.x) {
    int d = dst[e];
    int r = __hip_atomic_fetch_add(&plane[d], 1, __ATOMIC_RELAXED, __HIP_MEMORY_SCOPE_WORKGROUP);
    rank[e] = (ushort)((xcd << 13) | (uint)r);
  }
}

// ---------------- scan phase A: sum 8 planes -> degc total, dinv, blocksum ----------------
__global__ __launch_bounds__(SCAN_TPB) void k_scanA(const int* __restrict__ degc8, int N,
    int* __restrict__ degc, int* __restrict__ blocksum, float* __restrict__ dinv) {
  int ipt = (N + SCAN_NB*SCAN_TPB - 1) / (SCAN_NB*SCAN_TPB);
  int chunk = ipt * SCAN_TPB;
  int start = blockIdx.x * chunk + threadIdx.x * ipt;
  int s = 0;
  #pragma unroll
  for (int k = 0; k < 4; ++k) {
    if (k < ipt) {
      int i = start + k;
      if (i < N) {
        int d = 0;
        #pragma unroll
        for (int x = 0; x < 8; ++x) d += degc8[(size_t)x*N + i];
        degc[i] = d;
        s += d;
        dinv[i] = rsqrtf((float)d + 1.0f);
      }
    }
  }
  __shared__ int red[SCAN_TPB];
  int t = threadIdx.x;
  red[t] = s; __syncthreads();
  for (int off = SCAN_TPB/2; off > 0; off >>= 1) {
    if (t < off) red[t] += red[t+off];
    __syncthreads();
  }
  if (t == 0) blocksum[blockIdx.x] = red[0];
}

// ---------------- scan phase B (block 0) + graph bounds (block 1) ----------------
__global__ __launch_bounds__(SCAN_NB) void k_scanB(const int* __restrict__ blocksum,
    int* __restrict__ blockoff, int* __restrict__ totalN,
    const int* __restrict__ batch, int N, int G, float* __restrict__ inv_cnt) {
  int t = threadIdx.x;
  if (blockIdx.x == 0) {
    __shared__ int sh[SCAN_NB];
    sh[t] = blocksum[t];
    __syncthreads();
    for (int off = 1; off < SCAN_NB; off <<= 1) {
      int v = (t >= off) ? sh[t-off] : 0;
      __syncthreads();
      sh[t] += v;
      __syncthreads();
    }
    blockoff[t] = (t == 0) ? 0 : sh[t-1];
    if (t == SCAN_NB-1) *totalN = sh[t];
  } else {
    __shared__ int bnd[SCAN_NB+1];
    if (t <= G) {
      int lo = 0, hi = N;
      while (lo < hi) { int mid = (lo + hi) >> 1; if (batch[mid] < t) lo = mid + 1; else hi = mid; }
      bnd[t] = lo;
    }
    __syncthreads();
    if (t < G) {
      int c = bnd[t+1] - bnd[t];
      inv_cnt[t] = 1.0f / (float)max(c, 1);
    }
  }
}

// ---------------- scan phase C: row_ptr + per-XCD sub-offsets row_ptr8 ----------------
__global__ __launch_bounds__(SCAN_TPB) void k_scanC(const int* __restrict__ degc,
    const int* __restrict__ degc8, int N,
    const int* __restrict__ blockoff, const int* __restrict__ totalN,
    int* __restrict__ row_ptr, int* __restrict__ row_ptr8) {
  int ipt = (N + SCAN_NB*SCAN_TPB - 1) / (SCAN_NB*SCAN_TPB);
  int chunk = ipt * SCAN_TPB;
  int start = blockIdx.x * chunk + threadIdx.x * ipt;
  int t = threadIdx.x;
  int vals[4];
  int s = 0;
  #pragma unroll
  for (int k = 0; k < 4; ++k) {
    int v = 0;
    if (k < ipt) { int i = start + k; if (i < N) v = degc[i]; }
    vals[k] = v; s += v;
  }
  __shared__ int sh[SCAN_TPB];
  sh[t] = s; __syncthreads();
  for (int off = 1; off < SCAN_TPB; off <<= 1) {
    int v = (t >= off) ? sh[t-off] : 0;
    __syncthreads();
    sh[t] += v;
    __syncthreads();
  }
  int run = blockoff[blockIdx.x] + ((t == 0) ? 0 : sh[t-1]);
  #pragma unroll
  for (int k = 0; k < 4; ++k) {
    if (k < ipt) {
      int i = start + k;
      if (i < N) {
        row_ptr[i] = run;
        int c = run;
        #pragma unroll
        for (int x = 0; x < 8; ++x) {
          row_ptr8[(size_t)x*N + i] = c;
          c += degc8[(size_t)x*N + i];
        }
      }
    }
    run += vals[k];
  }
  if (blockIdx.x == 0 && t == 0) row_ptr[N] = *totalN;
}

// ---------------- fill CSR (atomic-free): pos = row_ptr8[xcd][dst] + r ----------------
__global__ __launch_bounds__(256) void k_fill(const int* __restrict__ src, const int* __restrict__ dst, int E, int N,
    const float* __restrict__ dinv, const int* __restrict__ row_ptr8, const ushort* __restrict__ rank,
    int2* __restrict__ epack) {
  for (int e = blockIdx.x*blockDim.x + threadIdx.x; e < E; e += gridDim.x*blockDim.x) {
    int s = src[e], d = dst[e];
    uint rk = rank[e];
    uint xcd = rk >> 13;
    int  r   = (int)(rk & 0x1FFFu);
    int pos = row_ptr8[(size_t)xcd*N + d] + r;
    float cf = dinv[s] * dinv[d];
    epack[pos] = make_int2(s, __float_as_int(cf));
  }
}

// ---------------- GEMM: xw(bf16) = in @ W; W frags from precomputed image ----------------
template<int IN_F32>
__global__ __launch_bounds__(256,1) void k_gemm(const void* __restrict__ in_, const ushort* __restrict__ wf,
    ushort* __restrict__ xw, int N) {
  int lane = threadIdx.x & 63;
  int wid  = (blockIdx.x * blockDim.x + threadIdx.x) >> 6;
  int nw   = (gridDim.x * blockDim.x) >> 6;
  int colB = lane & 15;
  int krow = (lane >> 4) * 8;

  short8 bfr[8][4];
  #pragma unroll
  for (int nt = 0; nt < 8; ++nt)
    #pragma unroll
    for (int kc = 0; kc < 4; ++kc)
      bfr[nt][kc] = *(const short8*)(wf + (((nt<<2) + kc) << 9) + (lane << 3));

  int strips = (N + 15) >> 4;
  for (int s = wid; s < strips; s += nw) {
    int ra = s*16 + colB;
    bool va = ra < N;
    short8 a[4];
    if (IN_F32) {
      const float* xin = (const float*)in_;
      #pragma unroll
      for (int kc = 0; kc < 4; ++kc) {
        short8 t = {0,0,0,0,0,0,0,0};
        if (va) {
          const float* p = xin + (size_t)ra*HDIM + kc*32 + krow;
          float4 lo4 = *(const float4*)p;
          float4 hi4 = *(const float4*)(p+4);
          t[0]=(short)f2bf(lo4.x); t[1]=(short)f2bf(lo4.y); t[2]=(short)f2bf(lo4.z); t[3]=(short)f2bf(lo4.w);
          t[4]=(short)f2bf(hi4.x); t[5]=(short)f2bf(hi4.y); t[6]=(short)f2bf(hi4.z); t[7]=(short)f2bf(hi4.w);
        }
        a[kc] = t;
      }
    } else {
      const ushort* hin = (const ushort*)in_;
      #pragma unroll
      for (int kc = 0; kc < 4; ++kc) {
        short8 t = {0,0,0,0,0,0,0,0};
        if (va) t = *(const short8*)(hin + (size_t)ra*HDIM + kc*32 + krow);
        a[kc] = t;
      }
    }
    f32x4 acc[8];
    #pragma unroll
    for (int nt = 0; nt < 8; ++nt) { acc[nt][0]=0.f; acc[nt][1]=0.f; acc[nt][2]=0.f; acc[nt][3]=0.f; }
    #pragma unroll
    for (int nt = 0; nt < 8; ++nt)
      #pragma unroll
      for (int kc = 0; kc < 4; ++kc)
        acc[nt] = __builtin_amdgcn_mfma_f32_16x16x32_bf16(a[kc], bfr[nt][kc], acc[nt], 0, 0, 0);

    int r0 = s*16 + (lane>>4)*4;
    #pragma unroll
    for (int nt = 0; nt < 8; ++nt) {
      int c = nt*16 + colB;
      #pragma unroll
      for (int rg = 0; rg < 4; ++rg) {
        int rr = r0 + rg;
        if (rr < N) xw[(size_t)rr*HDIM + c] = f2bf(acc[nt][rg]);
      }
    }
  }
}

// ---------------- aggregation (R12-proven): shfl-broadcast, 16 uniform-row gathers in flight ----------------
__global__ __launch_bounds__(256) void k_agg(const uint* __restrict__ xwu, const int2* __restrict__ epack,
    const int* __restrict__ row_ptr, const float* __restrict__ dinv, const float* __restrict__ bias,
    uint* __restrict__ hu, int N) {
  int lane = threadIdx.x & 63;
  int n = blockIdx.x*4 + (threadIdx.x >> 6);
  if (n >= N) return;
  int e0 = row_ptr[n], e1 = row_ptr[n+1];
  float a0 = 0.f, a1 = 0.f;
  for (int base = e0; base < e1; base += 64) {
    int cnt = min(64, e1 - base);
    int2 myp = make_int2(0, 0);            // lanes >= cnt: src=0, coef=0 (harmless dummy)
    if (lane < cnt) myp = epack[base + lane];
    for (int j = 0; j < cnt; j += 16) {
      #pragma unroll
      for (int u = 0; u < 16; ++u) {
        int idx = j + u;
        int   sN = __shfl(myp.x, idx);
        float cf = __int_as_float(__shfl(myp.y, idx));
        uint v = xwu[(size_t)sN*64 + lane];
        a0 += cf * bflo(v);
        a1 += cf * bfhi(v);
      }
    }
  }
  float di = dinv[n]; float w = di*di;
  uint v = xwu[(size_t)n*64 + lane];
  a0 += w * bflo(v);
  a1 += w * bfhi(v);
  a0 += bias[lane*2];  a1 += bias[lane*2+1];
  a0 = fmaxf(a0, 0.f); a1 = fmaxf(a1, 0.f);
  uint o = ((uint)f2bf(a0)) | (((uint)f2bf(a1)) << 16);
  hu[(size_t)n*64 + lane] = o;
}

// ---------------- pooling: segmented accumulate (batch sorted) ----------------
__global__ __launch_bounds__(256) void k_pool(const uint* __restrict__ hu, const int* __restrict__ batch,
    float* __restrict__ psum, int N) {
  int lane = threadIdx.x & 63;
  int wave = threadIdx.x >> 6;
  int n0 = blockIdx.x*512 + wave*128;
  if (n0 >= N) return;
  int n1 = min(n0 + 128, N);
  float a0 = 0.f, a1 = 0.f;
  int gc = batch[n0];
  for (int n = n0; n < n1; ++n) {
    int g = batch[n];
    if (g != gc) {
      atomicAdd(&psum[gc*HDIM + lane*2],   a0);
      atomicAdd(&psum[gc*HDIM + lane*2+1], a1);
      a0 = 0.f; a1 = 0.f; gc = g;
    }
    uint v = hu[(size_t)n*64 + lane];
    a0 += bflo(v); a1 += bfhi(v);
  }
  atomicAdd(&psum[gc*HDIM + lane*2],   a0);
  atomicAdd(&psum[gc*HDIM + lane*2+1], a1);
}

// ---------------- final linear ----------------
__global__ __launch_bounds__(256) void k_final(const float* __restrict__ psum, const float* __restrict__ inv_cnt,
    const float* __restrict__ Wlin, const float* __restrict__ blin, float* __restrict__ out, int G, int C) {
  int idx = blockIdx.x*256 + threadIdx.x;
  if (idx >= G*C) return;
  int g = idx / C, c = idx % C;
  float acc = 0.f;
  for (int k = 0; k < HDIM; ++k) acc += psum[g*HDIM + k] * Wlin[k*C + c];
  out[idx] = acc * inv_cnt[g] + blin[c];
}

extern "C" void kernel_launch(void* const* d_in, const int* in_sizes, int n_in,
                              void* d_out, int out_size, void* d_ws, size_t ws_size,
                              hipStream_t stream) {
  const float* x    = (const float*)d_in[0];
  const int*   ei   = (const int*)d_in[1];
  const int*   batch= (const int*)d_in[2];
  const float* W0   = (const float*)d_in[3];
  const float* b0   = (const float*)d_in[4];
  const float* W1   = (const float*)d_in[5];
  const float* b1   = (const float*)d_in[6];
  const float* W2   = (const float*)d_in[7];
  const float* b2   = (const float*)d_in[8];
  const float* Wlin = (const float*)d_in[9];
  const float* blin = (const float*)d_in[10];

  int N = in_sizes[0] / HDIM;
  int E = in_sizes[1] / 2;
  int C = in_sizes[10];
  int G = out_size / C;
  const int* src = ei;
  const int* dst = ei + E;

  char* ws = (char*)d_ws;
  size_t o = 0;
  auto alloc = [&](size_t bytes){ size_t r = o; o += (bytes + 511) & ~(size_t)511; return r; };
  size_t zbeg  = o;
  int*    degc8   = (int*)   (ws + alloc((size_t)8*N*4));
  float*  psum    = (float*) (ws + alloc((size_t)G*HDIM*4));
  size_t zend  = o;
  int*    degc    = (int*)   (ws + alloc((size_t)N*4));
  float*  dinv    = (float*) (ws + alloc((size_t)N*4));
  int*    row_ptr = (int*)   (ws + alloc((size_t)(N+1)*4));
  int*    row_ptr8= (int*)   (ws + alloc((size_t)8*N*4));
  float*  inv_cnt = (float*) (ws + alloc((size_t)G*4));
  int*    blocksum= (int*)   (ws + alloc((size_t)SCAN_NB*4));
  int*    blockoff= (int*)   (ws + alloc((size_t)SCAN_NB*4));
  int*    totalN  = (int*)   (ws + alloc(4));
  ushort* wf      = (ushort*)(ws + alloc((size_t)3*16384*2));
  ushort* rank    = (ushort*)(ws + alloc((size_t)E*2));
  int2*   epack   = (int2*)  (ws + alloc((size_t)E*8));
  ushort* xw      = (ushort*)(ws + alloc((size_t)N*HDIM*2));
  ushort* hbuf    = (ushort*)(ws + alloc((size_t)N*HDIM*2));

  hipMemsetAsync(ws + zbeg, 0, zend - zbeg, stream);

  k_wconv<<<24, 256, 0, stream>>>(W0, W1, W2, wf);
  k_deg  <<<2048, 256, 0, stream>>>(dst, E, N, degc8, rank);
  k_scanA<<<SCAN_NB, SCAN_TPB, 0, stream>>>(degc8, N, degc, blocksum, dinv);
  k_scanB<<<2, SCAN_NB, 0, stream>>>(blocksum, blockoff, totalN, batch, N, G, inv_cnt);
  k_scanC<<<SCAN_NB, SCAN_TPB, 0, stream>>>(degc, degc8, N, blockoff, totalN, row_ptr, row_ptr8);
  k_fill <<<2048, 256, 0, stream>>>(src, dst, E, N, dinv, row_ptr8, rank, epack);

  const int gemm_blocks = 512;
  const int agg_blocks  = (N + 3) / 4;

  // layer 0
  k_gemm<1><<<gemm_blocks, 256, 0, stream>>>((const void*)x, wf, xw, N);
  k_agg<<<agg_blocks, 256, 0, stream>>>((const uint*)xw, epack, row_ptr, dinv, b0, (uint*)hbuf, N);
  // layer 1
  k_gemm<0><<<gemm_blocks, 256, 0, stream>>>((const void*)hbuf, wf + 16384, xw, N);
  k_agg<<<agg_blocks, 256, 0, stream>>>((const uint*)xw, epack, row_ptr, dinv, b1, (uint*)hbuf, N);
  // layer 2
  k_gemm<0><<<gemm_blocks, 256, 0, stream>>>((const void*)hbuf, wf + 32768, xw, N);
  k_agg<<<agg_blocks, 256, 0, stream>>>((const uint*)xw, epack, row_ptr, dinv, b2, (uint*)hbuf, N);

  k_pool<<<(N + 511)/512, 256, 0, stream>>>((const uint*)hbuf, batch, psum, N);
  k_final<<<(G*C + 255)/256, 256, 0, stream>>>(psum, inv_cnt, Wlin, blin, (float*)d_out, G, C);
}

// Round 17
// 365.414 us; speedup vs baseline: 1.3655x; 1.0971x over previous
//
#include <hip/hip_runtime.h>

typedef short short8 __attribute__((ext_vector_type(8)));
typedef float f32x4 __attribute__((ext_vector_type(4)));
typedef float f32x2 __attribute__((ext_vector_type(2)));

#define HDIM 128
#define SCAN_NB 256
#define SCAN_TPB 256
// s_getreg imm: HW_REG_XCC_ID(=20) | offset 0<<6 | (32-1)<<11
#define XCC_GETREG_IMM (20 | (31 << 11))

__device__ __forceinline__ ushort f2bf(float f) {
  uint u = __float_as_uint(f);
  u += 0x7fffu + ((u >> 16) & 1u);   // round-to-nearest-even
  return (ushort)(u >> 16);
}
__device__ __forceinline__ float bflo(uint v){ return __uint_as_float(v << 16); }
__device__ __forceinline__ float bfhi(uint v){ return __uint_as_float(v & 0xffff0000u); }
__device__ __forceinline__ uchar f2fp8(float f) {
  int p = __builtin_amdgcn_cvt_pk_fp8_f32(f, f, 0, false);
  return (uchar)(p & 0xff);
}

// ---------------- W -> fragment-ordered bf16 image (once per launch, all 3 layers) ----------------
__global__ __launch_bounds__(256) void k_wconv(const float* __restrict__ W0, const float* __restrict__ W1,
    const float* __restrict__ W2, ushort* __restrict__ wf) {
  int b = blockIdx.x;
  const float* W = (b < 8) ? W0 : (b < 16) ? W1 : W2;
  ushort* out = wf + (size_t)(b >> 3) * 16384;
  int g = (b & 7) * 256 + threadIdx.x;      // group in [0, 2048)
  int nt = g >> 8, kc = (g >> 6) & 3, lane = g & 63;
  int colB = lane & 15, krow = (lane >> 4) * 8;
  ushort v[8];
  #pragma unroll
  for (int j = 0; j < 8; ++j)
    v[j] = f2bf(W[(kc*32 + krow + j)*HDIM + nt*16 + colB]);
  #pragma unroll
  for (int j = 0; j < 8; ++j) out[(size_t)g*8 + j] = v[j];
}

// ---------------- degree count, per-XCD partitions; local-L2 atomics ----------------
__global__ __launch_bounds__(256) void k_deg(const int* __restrict__ dst, int E, int N,
                                             int* __restrict__ degc8, ushort* __restrict__ rank) {
  uint xcd = __builtin_amdgcn_s_getreg(XCC_GETREG_IMM) & 7u;
  int* plane = degc8 + (size_t)xcd * N;
  for (int e = blockIdx.x*blockDim.x + threadIdx.x; e < E; e += gridDim.x*blockDim.x) {
    int d = dst[e];
    int r = __hip_atomic_fetch_add(&plane[d], 1, __ATOMIC_RELAXED, __HIP_MEMORY_SCOPE_WORKGROUP);
    rank[e] = (ushort)((xcd << 13) | (uint)r);
  }
}

// ---------------- scan phase A: sum 8 planes -> degc total, dinv, blocksum ----------------
__global__ __launch_bounds__(SCAN_TPB) void k_scanA(const int* __restrict__ degc8, int N,
    int* __restrict__ degc, int* __restrict__ blocksum, float* __restrict__ dinv) {
  int ipt = (N + SCAN_NB*SCAN_TPB - 1) / (SCAN_NB*SCAN_TPB);
  int chunk = ipt * SCAN_TPB;
  int start = blockIdx.x * chunk + threadIdx.x * ipt;
  int s = 0;
  #pragma unroll
  for (int k = 0; k < 4; ++k) {
    if (k < ipt) {
      int i = start + k;
      if (i < N) {
        int d = 0;
        #pragma unroll
        for (int x = 0; x < 8; ++x) d += degc8[(size_t)x*N + i];
        degc[i] = d;
        s += d;
        dinv[i] = rsqrtf((float)d + 1.0f);
      }
    }
  }
  __shared__ int red[SCAN_TPB];
  int t = threadIdx.x;
  red[t] = s; __syncthreads();
  for (int off = SCAN_TPB/2; off > 0; off >>= 1) {
    if (t < off) red[t] += red[t+off];
    __syncthreads();
  }
  if (t == 0) blocksum[blockIdx.x] = red[0];
}

// ---------------- scan phase B (block 0) + graph bounds (block 1) ----------------
__global__ __launch_bounds__(SCAN_NB) void k_scanB(const int* __restrict__ blocksum,
    int* __restrict__ blockoff, int* __restrict__ totalN,
    const int* __restrict__ batch, int N, int G, float* __restrict__ inv_cnt) {
  int t = threadIdx.x;
  if (blockIdx.x == 0) {
    __shared__ int sh[SCAN_NB];
    sh[t] = blocksum[t];
    __syncthreads();
    for (int off = 1; off < SCAN_NB; off <<= 1) {
      int v = (t >= off) ? sh[t-off] : 0;
      __syncthreads();
      sh[t] += v;
      __syncthreads();
    }
    blockoff[t] = (t == 0) ? 0 : sh[t-1];
    if (t == SCAN_NB-1) *totalN = sh[t];
  } else {
    __shared__ int bnd[SCAN_NB+1];
    if (t <= G) {
      int lo = 0, hi = N;
      while (lo < hi) { int mid = (lo + hi) >> 1; if (batch[mid] < t) lo = mid + 1; else hi = mid; }
      bnd[t] = lo;
    }
    __syncthreads();
    if (t < G) {
      int c = bnd[t+1] - bnd[t];
      inv_cnt[t] = 1.0f / (float)max(c, 1);
    }
  }
}

// ---------------- scan phase C: row_ptr + per-XCD sub-offsets row_ptr8 ----------------
__global__ __launch_bounds__(SCAN_TPB) void k_scanC(const int* __restrict__ degc,
    const int* __restrict__ degc8, int N,
    const int* __restrict__ blockoff, const int* __restrict__ totalN,
    int* __restrict__ row_ptr, int* __restrict__ row_ptr8) {
  int ipt = (N + SCAN_NB*SCAN_TPB - 1) / (SCAN_NB*SCAN_TPB);
  int chunk = ipt * SCAN_TPB;
  int start = blockIdx.x * chunk + threadIdx.x * ipt;
  int t = threadIdx.x;
  int vals[4];
  int s = 0;
  #pragma unroll
  for (int k = 0; k < 4; ++k) {
    int v = 0;
    if (k < ipt) { int i = start + k; if (i < N) v = degc[i]; }
    vals[k] = v; s += v;
  }
  __shared__ int sh[SCAN_TPB];
  sh[t] = s; __syncthreads();
  for (int off = 1; off < SCAN_TPB; off <<= 1) {
    int v = (t >= off) ? sh[t-off] : 0;
    __syncthreads();
    sh[t] += v;
    __syncthreads();
  }
  int run = blockoff[blockIdx.x] + ((t == 0) ? 0 : sh[t-1]);
  #pragma unroll
  for (int k = 0; k < 4; ++k) {
    if (k < ipt) {
      int i = start + k;
      if (i < N) {
        row_ptr[i] = run;
        int c = run;
        #pragma unroll
        for (int x = 0; x < 8; ++x) {
          row_ptr8[(size_t)x*N + i] = c;
          c += degc8[(size_t)x*N + i];
        }
      }
    }
    run += vals[k];
  }
  if (blockIdx.x == 0 && t == 0) row_ptr[N] = *totalN;
}

// ---------------- fill CSR (atomic-free): pos = row_ptr8[xcd][dst] + r ----------------
__global__ __launch_bounds__(256) void k_fill(const int* __restrict__ src, const int* __restrict__ dst, int E, int N,
    const float* __restrict__ dinv, const int* __restrict__ row_ptr8, const ushort* __restrict__ rank,
    int2* __restrict__ epack) {
  for (int e = blockIdx.x*blockDim.x + threadIdx.x; e < E; e += gridDim.x*blockDim.x) {
    int s = src[e], d = dst[e];
    uint rk = rank[e];
    uint xcd = rk >> 13;
    int  r   = (int)(rk & 0x1FFFu);
    int pos = row_ptr8[(size_t)xcd*N + d] + r;
    float cf = dinv[s] * dinv[d];
    epack[pos] = make_int2(s, __float_as_int(cf));
  }
}

// ---------------- GEMM: xw8(fp8 e4m3) = in @ W; W frags from precomputed image ----------------
template<int IN_F32>
__global__ __launch_bounds__(256,1) void k_gemm(const void* __restrict__ in_, const ushort* __restrict__ wf,
    uchar* __restrict__ xw8, int N) {
  int lane = threadIdx.x & 63;
  int wid  = (blockIdx.x * blockDim.x + threadIdx.x) >> 6;
  int nw   = (gridDim.x * blockDim.x) >> 6;
  int colB = lane & 15;
  int krow = (lane >> 4) * 8;

  short8 bfr[8][4];
  #pragma unroll
  for (int nt = 0; nt < 8; ++nt)
    #pragma unroll
    for (int kc = 0; kc < 4; ++kc)
      bfr[nt][kc] = *(const short8*)(wf + (((nt<<2) + kc) << 9) + (lane << 3));

  int strips = (N + 15) >> 4;
  for (int s = wid; s < strips; s += nw) {
    int ra = s*16 + colB;
    bool va = ra < N;
    short8 a[4];
    if (IN_F32) {
      const float* xin = (const float*)in_;
      #pragma unroll
      for (int kc = 0; kc < 4; ++kc) {
        short8 t = {0,0,0,0,0,0,0,0};
        if (va) {
          const float* p = xin + (size_t)ra*HDIM + kc*32 + krow;
          float4 lo4 = *(const float4*)p;
          float4 hi4 = *(const float4*)(p+4);
          t[0]=(short)f2bf(lo4.x); t[1]=(short)f2bf(lo4.y); t[2]=(short)f2bf(lo4.z); t[3]=(short)f2bf(lo4.w);
          t[4]=(short)f2bf(hi4.x); t[5]=(short)f2bf(hi4.y); t[6]=(short)f2bf(hi4.z); t[7]=(short)f2bf(hi4.w);
        }
        a[kc] = t;
      }
    } else {
      const ushort* hin = (const ushort*)in_;
      #pragma unroll
      for (int kc = 0; kc < 4; ++kc) {
        short8 t = {0,0,0,0,0,0,0,0};
        if (va) t = *(const short8*)(hin + (size_t)ra*HDIM + kc*32 + krow);
        a[kc] = t;
      }
    }
    f32x4 acc[8];
    #pragma unroll
    for (int nt = 0; nt < 8; ++nt) { acc[nt][0]=0.f; acc[nt][1]=0.f; acc[nt][2]=0.f; acc[nt][3]=0.f; }
    #pragma unroll
    for (int nt = 0; nt < 8; ++nt)
      #pragma unroll
      for (int kc = 0; kc < 4; ++kc)
        acc[nt] = __builtin_amdgcn_mfma_f32_16x16x32_bf16(a[kc], bfr[nt][kc], acc[nt], 0, 0, 0);

    int r0 = s*16 + (lane>>4)*4;
    #pragma unroll
    for (int nt = 0; nt < 8; ++nt) {
      int c = nt*16 + colB;
      #pragma unroll
      for (int rg = 0; rg < 4; ++rg) {
        int rr = r0 + rg;
        if (rr < N) xw8[(size_t)rr*HDIM + c] = f2fp8(acc[nt][rg]);
      }
    }
  }
}

// ---------------- aggregation: fp8 rows (128B/gather), shfl-broadcast, 16-deep ----------------
__global__ __launch_bounds__(256) void k_agg(const ushort* __restrict__ xw8u, const int2* __restrict__ epack,
    const int* __restrict__ row_ptr, const float* __restrict__ dinv, const float* __restrict__ bias,
    uint* __restrict__ hu, int N) {
  int lane = threadIdx.x & 63;
  int n = blockIdx.x*4 + (threadIdx.x >> 6);
  if (n >= N) return;
  int e0 = row_ptr[n], e1 = row_ptr[n+1];
  float a0 = 0.f, a1 = 0.f;
  for (int base = e0; base < e1; base += 64) {
    int cnt = min(64, e1 - base);
    int2 myp = make_int2(0, 0);            // lanes >= cnt: src=0, coef=0 (harmless dummy)
    if (lane < cnt) myp = epack[base + lane];
    for (int j = 0; j < cnt; j += 16) {
      #pragma unroll
      for (int u = 0; u < 16; ++u) {
        int idx = j + u;
        int   sN = __shfl(myp.x, idx);
        float cf = __int_as_float(__shfl(myp.y, idx));
        int v16 = (int)xw8u[(size_t)sN*64 + lane];     // 2 fp8 values
        f32x2 f = __builtin_amdgcn_cvt_pk_f32_fp8(v16, false);
        a0 += cf * f[0];
        a1 += cf * f[1];
      }
    }
  }
  float di = dinv[n]; float w = di*di;
  int v16s = (int)xw8u[(size_t)n*64 + lane];
  f32x2 fs = __builtin_amdgcn_cvt_pk_f32_fp8(v16s, false);
  a0 += w * fs[0];
  a1 += w * fs[1];
  a0 += bias[lane*2];  a1 += bias[lane*2+1];
  a0 = fmaxf(a0, 0.f); a1 = fmaxf(a1, 0.f);
  uint o = ((uint)f2bf(a0)) | (((uint)f2bf(a1)) << 16);
  hu[(size_t)n*64 + lane] = o;
}

// ---------------- pooling: segmented accumulate (batch sorted) ----------------
__global__ __launch_bounds__(256) void k_pool(const uint* __restrict__ hu, const int* __restrict__ batch,
    float* __restrict__ psum, int N) {
  int lane = threadIdx.x & 63;
  int wave = threadIdx.x >> 6;
  int n0 = blockIdx.x*512 + wave*128;
  if (n0 >= N) return;
  int n1 = min(n0 + 128, N);
  float a0 = 0.f, a1 = 0.f;
  int gc = batch[n0];
  for (int n = n0; n < n1; ++n) {
    int g = batch[n];
    if (g != gc) {
      atomicAdd(&psum[gc*HDIM + lane*2],   a0);
      atomicAdd(&psum[gc*HDIM + lane*2+1], a1);
      a0 = 0.f; a1 = 0.f; gc = g;
    }
    uint v = hu[(size_t)n*64 + lane];
    a0 += bflo(v); a1 += bfhi(v);
  }
  atomicAdd(&psum[gc*HDIM + lane*2],   a0);
  atomicAdd(&psum[gc*HDIM + lane*2+1], a1);
}

// ---------------- final linear ----------------
__global__ __launch_bounds__(256) void k_final(const float* __restrict__ psum, const float* __restrict__ inv_cnt,
    const float* __restrict__ Wlin, const float* __restrict__ blin, float* __restrict__ out, int G, int C) {
  int idx = blockIdx.x*256 + threadIdx.x;
  if (idx >= G*C) return;
  int g = idx / C, c = idx % C;
  float acc = 0.f;
  for (int k = 0; k < HDIM; ++k) acc += psum[g*HDIM + k] * Wlin[k*C + c];
  out[idx] = acc * inv_cnt[g] + blin[c];
}

extern "C" void kernel_launch(void* const* d_in, const int* in_sizes, int n_in,
                              void* d_out, int out_size, void* d_ws, size_t ws_size,
                              hipStream_t stream) {
  const float* x    = (const float*)d_in[0];
  const int*   ei   = (const int*)d_in[1];
  const int*   batch= (const int*)d_in[2];
  const float* W0   = (const float*)d_in[3];
  const float* b0   = (const float*)d_in[4];
  const float* W1   = (const float*)d_in[5];
  const float* b1   = (const float*)d_in[6];
  const float* W2   = (const float*)d_in[7];
  const float* b2   = (const float*)d_in[8];
  const float* Wlin = (const float*)d_in[9];
  const float* blin = (const float*)d_in[10];

  int N = in_sizes[0] / HDIM;
  int E = in_sizes[1] / 2;
  int C = in_sizes[10];
  int G = out_size / C;
  const int* src = ei;
  const int* dst = ei + E;

  char* ws = (char*)d_ws;
  size_t o = 0;
  auto alloc = [&](size_t bytes){ size_t r = o; o += (bytes + 511) & ~(size_t)511; return r; };
  size_t zbeg  = o;
  int*    degc8   = (int*)   (ws + alloc((size_t)8*N*4));
  float*  psum    = (float*) (ws + alloc((size_t)G*HDIM*4));
  size_t zend  = o;
  int*    degc    = (int*)   (ws + alloc((size_t)N*4));
  float*  dinv    = (float*) (ws + alloc((size_t)N*4));
  int*    row_ptr = (int*)   (ws + alloc((size_t)(N+1)*4));
  int*    row_ptr8= (int*)   (ws + alloc((size_t)8*N*4));
  float*  inv_cnt = (float*) (ws + alloc((size_t)G*4));
  int*    blocksum= (int*)   (ws + alloc((size_t)SCAN_NB*4));
  int*    blockoff= (int*)   (ws + alloc((size_t)SCAN_NB*4));
  int*    totalN  = (int*)   (ws + alloc(4));
  ushort* wf      = (ushort*)(ws + alloc((size_t)3*16384*2));
  ushort* rank    = (ushort*)(ws + alloc((size_t)E*2));
  int2*   epack   = (int2*)  (ws + alloc((size_t)E*8));
  uchar*  xw8     = (uchar*) (ws + alloc((size_t)N*HDIM));
  ushort* hbuf    = (ushort*)(ws + alloc((size_t)N*HDIM*2));

  hipMemsetAsync(ws + zbeg, 0, zend - zbeg, stream);

  k_wconv<<<24, 256, 0, stream>>>(W0, W1, W2, wf);
  k_deg  <<<2048, 256, 0, stream>>>(dst, E, N, degc8, rank);
  k_scanA<<<SCAN_NB, SCAN_TPB, 0, stream>>>(degc8, N, degc, blocksum, dinv);
  k_scanB<<<2, SCAN_NB, 0, stream>>>(blocksum, blockoff, totalN, batch, N, G, inv_cnt);
  k_scanC<<<SCAN_NB, SCAN_TPB, 0, stream>>>(degc, degc8, N, blockoff, totalN, row_ptr, row_ptr8);
  k_fill <<<2048, 256, 0, stream>>>(src, dst, E, N, dinv, row_ptr8, rank, epack);

  const int gemm_blocks = 512;
  const int agg_blocks  = (N + 3) / 4;

  // layer 0
  k_gemm<1><<<gemm_blocks, 256, 0, stream>>>((const void*)x, wf, xw8, N);
  k_agg<<<agg_blocks, 256, 0, stream>>>((const ushort*)xw8, epack, row_ptr, dinv, b0, (uint*)hbuf, N);
  // layer 1
  k_gemm<0><<<gemm_blocks, 256, 0, stream>>>((const void*)hbuf, wf + 16384, xw8, N);
  k_agg<<<agg_blocks, 256, 0, stream>>>((const ushort*)xw8, epack, row_ptr, dinv, b1, (uint*)hbuf, N);
  // layer 2
  k_gemm<0><<<gemm_blocks, 256, 0, stream>>>((const void*)hbuf, wf + 32768, xw8, N);
  k_agg<<<agg_blocks, 256, 0, stream>>>((const ushort*)xw8, epack, row_ptr, dinv, b2, (uint*)hbuf, N);

  k_pool<<<(N + 511)/512, 256, 0, stream>>>((const uint*)hbuf, batch, psum, N);
  k_final<<<(G*C + 255)/256, 256, 0, stream>>>(psum, inv_cnt, Wlin, blin, (float*)d_out, G, C);
}